// Round 7
// baseline (405.621 us; speedup 1.0000x reference)
//
#include <hip/hip_runtime.h>
#include <cstdint>
#include <cstddef>

typedef __attribute__((ext_vector_type(4))) float f32x4;

#define LOG2E 1.44269504088896340736f

constexpr int N_ = 8;
constexpr int S_ = 2048;
constexpr int D_ = 64;   // head dim == value dim == 64

__device__ __forceinline__ float bfbits(uint lo16) {   // bf16 bit pattern -> fp32 (exact)
    return __builtin_bit_cast(float, lo16 << 16);
}

// One wave per query row; 4 rows per block. K/V tiles (64 keys x 64 dims)
// staged in LDS and shared by the block's 4 waves. All math in fp32.
// OUTPUT IS FP32 (reference output dtype). Input dtype (fp32 vs bf16
// storage) and prefix_len dtype (int32 vs int64) sniffed on-device.
__global__ __launch_bounds__(256) void attn_naive(
    const void* __restrict__ Qp, const void* __restrict__ Kp,
    const void* __restrict__ Vp, const int* __restrict__ plen,
    float* __restrict__ outm)
{
    __shared__ float Kt[64][67];   // 67-float stride: <=2-way bank aliasing (free)
    __shared__ float Vt[64][67];
    __shared__ float invs[4];

    const int n    = blockIdx.y;
    const int bx   = blockIdx.x;
    const int tid  = threadIdx.x;
    const int w    = tid >> 6;        // wave id = which of 4 query rows
    const int lane = tid & 63;
    const int q    = bx * 4 + w;      // this wave's query row

    // ---- input dtype sniff (uniform across threads; 128B, L1-hot) ----
    // fp32 data: low ushort of each word is uniform mantissa bits -> the
    // bf16-exponent-field test [0x90,0xFE] hits quickly. True bf16 N(0,1)
    // data: exponent <= ~0x82, never hits. All-zero low halves => fp32
    // storage of bf16-rounded values.
    bool isf32 = false, allz = true;
    {
        const ushort* k16 = (const ushort*)Kp;
        for (int i = 0; i < 64; i++) {
            ushort u = k16[2 * i];
            uint e = (u >> 7) & 0xFFu;
            if (e >= 0x90u && e <= 0xFEu) isf32 = true;
            if (u != 0) allz = false;
        }
        if (allz) isf32 = true;
    }
    // ---- prefix_len dtype sniff: int64 lo/hi words vs int32 values ----
    const bool is64 = ((plen[1] | plen[3] | plen[5] | plen[7]) == 0);
    const int prefix = is64 ? plen[2 * n] : plen[n];

    // ---- load this wave's full Q row into registers (fp32) ----
    float qreg[64];
    if (isf32) {
        const float* qr = (const float*)Qp + (size_t)(n * S_ + q) * D_;
#pragma unroll
        for (int i = 0; i < 16; i++) {
            f32x4 t = *reinterpret_cast<const f32x4*>(qr + i * 4);
            qreg[i * 4 + 0] = t[0]; qreg[i * 4 + 1] = t[1];
            qreg[i * 4 + 2] = t[2]; qreg[i * 4 + 3] = t[3];
        }
    } else {
        const ushort* qr = (const ushort*)Qp + (size_t)(n * S_ + q) * D_;
#pragma unroll
        for (int i = 0; i < 8; i++) {
            uint4 u = *reinterpret_cast<const uint4*>(qr + i * 8);
            qreg[i * 8 + 0] = bfbits(u.x & 0xFFFFu);
            qreg[i * 8 + 1] = __builtin_bit_cast(float, u.x & 0xFFFF0000u);
            qreg[i * 8 + 2] = bfbits(u.y & 0xFFFFu);
            qreg[i * 8 + 3] = __builtin_bit_cast(float, u.y & 0xFFFF0000u);
            qreg[i * 8 + 4] = bfbits(u.z & 0xFFFFu);
            qreg[i * 8 + 5] = __builtin_bit_cast(float, u.z & 0xFFFF0000u);
            qreg[i * 8 + 6] = bfbits(u.w & 0xFFFFu);
            qreg[i * 8 + 7] = __builtin_bit_cast(float, u.w & 0xFFFF0000u);
        }
    }

    float m = -1e30f, l = 0.f;
    float o[64];
#pragma unroll
    for (int v = 0; v < 64; v++) o[v] = 0.f;

    const int nT = (prefix + 63) / 64;   // 64-key tiles covering the prefix
    const int dt = (bx * 4) >> 6;        // diagonal tile (uniform for block)
    const int total = nT + ((dt >= nT) ? 1 : 0);

    const int rt = tid >> 2;             // staging: row this thread loads
    const int cb = (tid & 3) * 16;       // staging: 16-col chunk

    for (int it = 0; it < total; it++) {
        const int kb = ((it < nT) ? it : dt) * 64;

        __syncthreads();   // previous tile fully consumed before overwrite
        if (isf32) {
            const float* kr = (const float*)Kp + (size_t)(n * S_ + kb + rt) * D_ + cb;
            const float* vr = (const float*)Vp + (size_t)(n * S_ + kb + rt) * D_ + cb;
#pragma unroll
            for (int i = 0; i < 4; i++) {
                f32x4 a = *reinterpret_cast<const f32x4*>(kr + i * 4);
                f32x4 b = *reinterpret_cast<const f32x4*>(vr + i * 4);
#pragma unroll
                for (int j = 0; j < 4; j++) {
                    Kt[rt][cb + i * 4 + j] = a[j];
                    Vt[rt][cb + i * 4 + j] = b[j];
                }
            }
        } else {
            const ushort* kr = (const ushort*)Kp + (size_t)(n * S_ + kb + rt) * D_ + cb;
            const ushort* vr = (const ushort*)Vp + (size_t)(n * S_ + kb + rt) * D_ + cb;
#pragma unroll
            for (int i = 0; i < 2; i++) {
                uint4 a = *reinterpret_cast<const uint4*>(kr + i * 8);
                uint4 b = *reinterpret_cast<const uint4*>(vr + i * 8);
                const uint ka[4] = {a.x, a.y, a.z, a.w};
                const uint vb[4] = {b.x, b.y, b.z, b.w};
#pragma unroll
                for (int j = 0; j < 4; j++) {
                    Kt[rt][cb + i * 8 + 2 * j]     = bfbits(ka[j] & 0xFFFFu);
                    Kt[rt][cb + i * 8 + 2 * j + 1] = __builtin_bit_cast(float, ka[j] & 0xFFFF0000u);
                    Vt[rt][cb + i * 8 + 2 * j]     = bfbits(vb[j] & 0xFFFFu);
                    Vt[rt][cb + i * 8 + 2 * j + 1] = __builtin_bit_cast(float, vb[j] & 0xFFFF0000u);
                }
            }
        }
        __syncthreads();

        // ---- per-wave compute: lane = key within tile ----
        float s0 = 0.f, s1 = 0.f, s2 = 0.f, s3 = 0.f;
#pragma unroll
        for (int d = 0; d < 64; d += 4) {
            s0 += qreg[d + 0] * Kt[lane][d + 0];
            s1 += qreg[d + 1] * Kt[lane][d + 1];
            s2 += qreg[d + 2] * Kt[lane][d + 2];
            s3 += qreg[d + 3] * Kt[lane][d + 3];
        }
        float s = ((s0 + s1) + (s2 + s3)) * 0.125f;   // 1/sqrt(64)
        const int key = kb + lane;
        const bool ok = (key < prefix) || (key == q);
        s = ok ? s : -1e30f;

        float smax = s;
#pragma unroll
        for (int off = 1; off < 64; off <<= 1)
            smax = fmaxf(smax, __shfl_xor(smax, off, 64));
        const float mnew = fmaxf(m, smax);
        const float alpha = exp2f((m - mnew) * LOG2E);
        const float p = ok ? exp2f((s - mnew) * LOG2E) : 0.f;
        float ps = p;
#pragma unroll
        for (int off = 1; off < 64; off <<= 1)
            ps += __shfl_xor(ps, off, 64);
        l = l * alpha + ps;
        m = mnew;
#pragma unroll
        for (int v = 0; v < 64; v++)
            o[v] = fmaf(p, Vt[lane][v], o[v] * alpha);
    }

    // ---- merge: lane-partial O reduced through LDS, two rounds ----
    __syncthreads();
    if (lane == 0) invs[w] = 1.f / l;      // l > 0: diagonal never masked

    if (w < 2) {
        float* dst = (w == 0) ? &Kt[0][0] : &Vt[0][0];
#pragma unroll
        for (int v = 0; v < 64; v++) dst[lane * 67 + v] = o[v];
    }
    __syncthreads();
    if (tid < 128) {
        const int w2 = tid >> 6, v = tid & 63;
        const float* src = (w2 == 0) ? &Kt[0][0] : &Vt[0][0];
        float sum = 0.f;
        for (int ll = 0; ll < 64; ll++) sum += src[ll * 67 + v];
        outm[(size_t)(n * S_ + bx * 4 + w2) * D_ + v] = sum * invs[w2];
    }
    __syncthreads();
    if (w >= 2) {
        float* dst = (w == 2) ? &Kt[0][0] : &Vt[0][0];
#pragma unroll
        for (int v = 0; v < 64; v++) dst[lane * 67 + v] = o[v];
    }
    __syncthreads();
    if (tid < 128) {
        const int w2 = 2 + (tid >> 6), v = tid & 63;
        const float* src = (w2 == 2) ? &Kt[0][0] : &Vt[0][0];
        float sum = 0.f;
        for (int ll = 0; ll < 64; ll++) sum += src[ll * 67 + v];
        outm[(size_t)(n * S_ + bx * 4 + w2) * D_ + v] = sum * invs[w2];
    }
}

extern "C" void kernel_launch(void* const* d_in, const int* in_sizes, int n_in,
                              void* d_out, int out_size, void* d_ws, size_t ws_size,
                              hipStream_t stream) {
    const void* Qp = d_in[0];
    const void* Kp = d_in[1];
    const void* Vp = d_in[2];
    const int* plen = (const int*)d_in[3];
    float* outm = (float*)d_out;   // reference output dtype is float32

    dim3 grid(S_ / 4, N_);   // 512 x 8 blocks, 4 query rows per block
    attn_naive<<<grid, 256, 0, stream>>>(Qp, Kp, Vp, plen, outm);
}

// Round 8
// 116.614 us; speedup vs baseline: 3.4783x; 3.4783x over previous
//
#include <hip/hip_runtime.h>
#include <cstdint>
#include <cstddef>

typedef __attribute__((ext_vector_type(8))) __bf16 bf16x8;
typedef __attribute__((ext_vector_type(4))) float f32x4;

#define LOG2E 1.44269504088896340736f
// Compiler-ordering barrier for the cross-lane LDS round trip (per-thread
// alias analysis can't see lane-crossed data flow).
#define LDS_ORDER() __asm__ __volatile__("" ::: "memory")

constexpr int N_ = 8;
constexpr int S_ = 2048;
constexpr int D_ = 64;
constexpr int V_ = 64;
constexpr int TQ = 16;   // queries per block
constexpr int CK = 32;   // keys per chunk
constexpr int NW = 4;    // waves per block (K-split)

__device__ __forceinline__ ushort f2bf(float x) {      // fp32 -> bf16 RNE
    uint u = __builtin_bit_cast(uint, x);
    return (ushort)((u + 0x7FFFu + ((u >> 16) & 1u)) >> 16);
}
__device__ __forceinline__ bf16x8 ld8(const ushort* p) {
    uint4 u = *reinterpret_cast<const uint4*>(p);
    return __builtin_bit_cast(bf16x8, u);
}
__device__ __forceinline__ bf16x8 cvt8(const float* p) {
    f32x4 a = *reinterpret_cast<const f32x4*>(p);
    f32x4 b = *reinterpret_cast<const f32x4*>(p + 4);
    bf16x8 r;
#pragma unroll
    for (int j = 0; j < 4; j++) { r[j] = static_cast<__bf16>(a[j]); r[j + 4] = static_cast<__bf16>(b[j]); }
    return r;
}

// prefix_len dtype sniff (int64 iff hi-words all zero; values < 2048).
__device__ __forceinline__ int load_prefix(const int* plen, int n) {
    bool is64 = ((plen[1] | plen[3] | plen[5] | plen[7]) == 0);
    return is64 ? plen[2 * n] : plen[n];
}

// fp32 Q/K/V -> bf16 Qb/Kb (same layout) + bf16 VT[n][v][s] (transposed)
__global__ void prep_kernel(const float* __restrict__ Q, const float* __restrict__ K,
                            const float* __restrict__ V, ushort* __restrict__ Qb,
                            ushort* __restrict__ Kb, ushort* __restrict__ VTb) {
    const int i4 = (blockIdx.x * 256 + threadIdx.x) * 4;   // over N*S*64 = 2^20 elems
    f32x4 q = *reinterpret_cast<const f32x4*>(Q + i4);
    f32x4 k = *reinterpret_cast<const f32x4*>(K + i4);
    f32x4 v = *reinterpret_cast<const f32x4*>(V + i4);
    ushort4 qo, ko;
    qo.x = f2bf(q[0]); qo.y = f2bf(q[1]); qo.z = f2bf(q[2]); qo.w = f2bf(q[3]);
    ko.x = f2bf(k[0]); ko.y = f2bf(k[1]); ko.z = f2bf(k[2]); ko.w = f2bf(k[3]);
    *reinterpret_cast<ushort4*>(Qb + i4) = qo;
    *reinterpret_cast<ushort4*>(Kb + i4) = ko;
    const int vd = i4 & (V_ - 1);
    const int s  = (i4 >> 6) & (S_ - 1);
    const int n  = i4 >> 17;
#pragma unroll
    for (int j = 0; j < 4; j++)
        VTb[((size_t)(n * V_ + vd + j)) * S_ + s] = f2bf(v[j]);
}

template <bool WS>
__global__ __launch_bounds__(256, 4) void attn_kernel(
    const void* __restrict__ Qp, const void* __restrict__ Kp,
    const void* __restrict__ Vp, const ushort* __restrict__ VTb,
    const int* __restrict__ plen, float* __restrict__ outm)
{
    __shared__ float obuf[NW][TQ][V_ + 4];          // +4 pad
    __shared__ float mbuf[NW][TQ];
    __shared__ float lbuf[NW][TQ];
    __shared__ alignas(16) __bf16 pbuf[NW][TQ][40]; // P scratch, 40-elem stride

    const int n    = blockIdx.y;
    const int q0   = blockIdx.x * TQ;
    const int tid  = threadIdx.x;
    const int w    = tid >> 6;
    const int lane = tid & 63;
    const int quad = lane >> 4;
    const int l16  = lane & 15;
    const int prefix = load_prefix(plen, n);

    // Q A-fragments: lane holds Q[q0+l16][quad*8 + (0..7)] (+32 for qf1)
    bf16x8 qf0, qf1;
    if (WS) {
        const ushort* qptr = (const ushort*)Qp + ((size_t)(n * S_ + q0 + l16)) * D_ + quad * 8;
        qf0 = ld8(qptr); qf1 = ld8(qptr + 32);
    } else {
        const float* qptr = (const float*)Qp + ((size_t)(n * S_ + q0 + l16)) * D_ + quad * 8;
        qf0 = cvt8(qptr); qf1 = cvt8(qptr + 32);
    }

    f32x4 oacc[4];
#pragma unroll
    for (int vb = 0; vb < 4; vb++) oacc[vb] = (f32x4){0.f, 0.f, 0.f, 0.f};
    float m_r[4], l_r[4];
#pragma unroll
    for (int r = 0; r < 4; r++) { m_r[r] = -1e30f; l_r[r] = 0.f; }

    const int nPC = (prefix + CK - 1) / CK;  // chunks covering the prefix
    const int dc  = q0 / CK;                 // chunk holding this tile's diagonal

    auto process = [&](int kb) {
        // K B-fragments (B = K^T: read K rows, contiguous in d)
        bf16x8 kf00, kf01, kf10, kf11;
        if (WS) {
            const ushort* kptr = (const ushort*)Kp + ((size_t)(n * S_ + kb + l16)) * D_ + quad * 8;
            kf00 = ld8(kptr);            kf01 = ld8(kptr + 32);
            kf10 = ld8(kptr + 16 * D_);  kf11 = ld8(kptr + 16 * D_ + 32);
        } else {
            const float* kptr = (const float*)Kp + ((size_t)(n * S_ + kb + l16)) * D_ + quad * 8;
            kf00 = cvt8(kptr);           kf01 = cvt8(kptr + 32);
            kf10 = cvt8(kptr + 16 * D_); kf11 = cvt8(kptr + 16 * D_ + 32);
        }

        const f32x4 zero = (f32x4){0.f, 0.f, 0.f, 0.f};
        f32x4 s0 = __builtin_amdgcn_mfma_f32_16x16x32_bf16(qf0, kf00, zero, 0, 0, 0);
        s0 = __builtin_amdgcn_mfma_f32_16x16x32_bf16(qf1, kf01, s0, 0, 0, 0);
        f32x4 s1 = __builtin_amdgcn_mfma_f32_16x16x32_bf16(qf0, kf10, zero, 0, 0, 0);
        s1 = __builtin_amdgcn_mfma_f32_16x16x32_bf16(qf1, kf11, s1, 0, 0, 0);
        // C layout: lane holds S[quad*4 + r][t*16 + l16]

        float sv[2][4];
        bool ok[2][4];
#pragma unroll
        for (int t = 0; t < 2; t++) {
#pragma unroll
            for (int r = 0; r < 4; r++) {
                float x = (t ? s1[r] : s0[r]) * 0.125f;   // 1/sqrt(64)
                int key  = kb + t * 16 + l16;
                int qrow = q0 + quad * 4 + r;
                bool v_ = (key < prefix) || (key == qrow);
                ok[t][r] = v_;
                sv[t][r] = v_ ? x : -1e30f;
            }
        }
        float rmax[4];
#pragma unroll
        for (int r = 0; r < 4; r++) rmax[r] = fmaxf(sv[0][r], sv[1][r]);
#pragma unroll
        for (int off = 1; off <= 8; off <<= 1) {
#pragma unroll
            for (int r = 0; r < 4; r++)
                rmax[r] = fmaxf(rmax[r], __shfl_xor(rmax[r], off, 64));
        }
        float alpha[4];
#pragma unroll
        for (int r = 0; r < 4; r++) {
            float mn = fmaxf(m_r[r], rmax[r]);
            alpha[r] = exp2f((m_r[r] - mn) * LOG2E);
            m_r[r] = mn;
        }
        float p[2][4], ps[4];
#pragma unroll
        for (int r = 0; r < 4; r++) ps[r] = 0.f;
#pragma unroll
        for (int t = 0; t < 2; t++) {
#pragma unroll
            for (int r = 0; r < 4; r++) {
                p[t][r] = ok[t][r] ? exp2f((sv[t][r] - m_r[r]) * LOG2E) : 0.f;
                ps[r] += p[t][r];
            }
        }
#pragma unroll
        for (int off = 1; off <= 8; off <<= 1) {
#pragma unroll
            for (int r = 0; r < 4; r++) ps[r] += __shfl_xor(ps[r], off, 64);
        }
#pragma unroll
        for (int r = 0; r < 4; r++) l_r[r] = l_r[r] * alpha[r] + ps[r];
#pragma unroll
        for (int vb = 0; vb < 4; vb++) {
#pragma unroll
            for (int r = 0; r < 4; r++) oacc[vb][r] *= alpha[r];
        }
        // P: C-layout -> A-layout via per-wave LDS round trip
        LDS_ORDER();
#pragma unroll
        for (int t = 0; t < 2; t++) {
#pragma unroll
            for (int r = 0; r < 4; r++)
                pbuf[w][quad * 4 + r][t * 16 + l16] = __builtin_bit_cast(__bf16, f2bf(p[t][r]));
        }
        LDS_ORDER();
        const bf16x8 pf = *reinterpret_cast<const bf16x8*>(&pbuf[w][l16][quad * 8]);
#pragma unroll
        for (int vb = 0; vb < 4; vb++) {
            bf16x8 vf;
            if (WS) {
                vf = ld8(VTb + ((size_t)(n * V_ + vb * 16 + l16)) * S_ + kb + quad * 8);
            } else {
                const float* vsrc = (const float*)Vp;
#pragma unroll
                for (int j = 0; j < 8; j++)
                    vf[j] = static_cast<__bf16>(
                        vsrc[((size_t)(n * S_ + kb + quad * 8 + j)) * V_ + vb * 16 + l16]);
            }
            oacc[vb] = __builtin_amdgcn_mfma_f32_16x16x32_bf16(pf, vf, oacc[vb], 0, 0, 0);
        }
    };

    for (int c = w; c < nPC; c += NW) process(c * CK);
    if (dc >= nPC && (dc & (NW - 1)) == w) process(dc * CK);

    if (l16 == 0) {
#pragma unroll
        for (int r = 0; r < 4; r++) {
            mbuf[w][quad * 4 + r] = m_r[r];
            lbuf[w][quad * 4 + r] = l_r[r];
        }
    }
#pragma unroll
    for (int vb = 0; vb < 4; vb++) {
#pragma unroll
        for (int r = 0; r < 4; r++)
            obuf[w][quad * 4 + r][vb * 16 + l16] = oacc[vb][r];
    }
    __syncthreads();

    // merge 4 K-split partials: thread -> (row, 4 v-dims); fp32 output
    const int row = tid >> 4;
    const int vd0 = (tid & 15) * 4;
    float mg = fmaxf(fmaxf(mbuf[0][row], mbuf[1][row]),
                     fmaxf(mbuf[2][row], mbuf[3][row]));
    float lg = 0.f;
    float acc[4] = {0.f, 0.f, 0.f, 0.f};
#pragma unroll
    for (int ww = 0; ww < NW; ww++) {
        float sc = exp2f((mbuf[ww][row] - mg) * LOG2E);
        lg += lbuf[ww][row] * sc;
#pragma unroll
        for (int i = 0; i < 4; i++) acc[i] += obuf[ww][row][vd0 + i] * sc;
    }
    float inv = 1.f / lg;   // lg > 0: diagonal key never masked
    f32x4 o4 = (f32x4){acc[0] * inv, acc[1] * inv, acc[2] * inv, acc[3] * inv};
    *reinterpret_cast<f32x4*>(outm + ((size_t)(n * S_ + q0 + row)) * V_ + vd0) = o4;
}

extern "C" void kernel_launch(void* const* d_in, const int* in_sizes, int n_in,
                              void* d_out, int out_size, void* d_ws, size_t ws_size,
                              hipStream_t stream) {
    // World C (verified R7): fp32 Q/K/V, int32 prefix_len (sniffed anyway),
    // fp32 output.
    const float* Qf = (const float*)d_in[0];
    const float* Kf = (const float*)d_in[1];
    const float* Vf = (const float*)d_in[2];
    const int* plen = (const int*)d_in[3];
    float* outm = (float*)d_out;

    constexpr size_t ELEMS = (size_t)N_ * S_ * D_;        // 2^20
    const size_t need = 3 * ELEMS * sizeof(ushort);       // Qb + Kb + VT = 6 MB
    dim3 agrid(S_ / TQ, N_);                              // 128 x 8

    if (ws_size >= need) {
        ushort* Qb  = (ushort*)d_ws;
        ushort* Kb  = Qb + ELEMS;
        ushort* VTb = Kb + ELEMS;
        prep_kernel<<<ELEMS / (256 * 4), 256, 0, stream>>>(Qf, Kf, Vf, Qb, Kb, VTb);
        attn_kernel<true><<<agrid, 256, 0, stream>>>(Qb, Kb, nullptr, VTb, plen, outm);
    } else {
        attn_kernel<false><<<agrid, 256, 0, stream>>>(Qf, Kf, Vf, nullptr, plen, outm);
    }
}